// Round 4
// baseline (4583.598 us; speedup 1.0000x reference)
//
#include <hip/hip_runtime.h>
#include <cstdint>
#include <cstddef>

#define B_   64
#define T_   2048
#define C_   64
#define H_   256
#define G3_  768    // 3*H
#define HOR_ 96

typedef _Float16 h2 __attribute__((ext_vector_type(2)));
typedef _Float16 h8 __attribute__((ext_vector_type(8)));
typedef _Float16 f16x8 __attribute__((ext_vector_type(8)));
typedef float f32x4 __attribute__((ext_vector_type(4)));

// ---------------------------------------------------------------------------
// K1: cur[b,t,h] = sum_c x[b,t,c]*snn_w[h,c] + snn_b[h]     (fp32)
// ---------------------------------------------------------------------------
#define K1_TT 128
__global__ __launch_bounds__(256) void k_cur(const float* __restrict__ x,
                                             const float* __restrict__ w,
                                             const float* __restrict__ bias,
                                             float* __restrict__ cur) {
  __shared__ float xs[K1_TT * C_];  // 32 KB
  const int b = blockIdx.x;
  const int t0 = blockIdx.y * K1_TT;
  const int tid = threadIdx.x;

  const float4* xsrc = (const float4*)(x + ((size_t)b * T_ + t0) * C_);
  float4* xdst = (float4*)xs;
#pragma unroll
  for (int i = 0; i < (K1_TT * C_ / 4) / 256; i++)
    xdst[tid + i * 256] = xsrc[tid + i * 256];

  float wr[C_];
  const float4* wp = (const float4*)(w + (size_t)tid * C_);
#pragma unroll
  for (int q = 0; q < C_ / 4; q++) {
    float4 v = wp[q];
    wr[4 * q + 0] = v.x; wr[4 * q + 1] = v.y;
    wr[4 * q + 2] = v.z; wr[4 * q + 3] = v.w;
  }
  const float bb = bias[tid];
  __syncthreads();

  for (int t = 0; t < K1_TT; t++) {
    const float4* xrow = (const float4*)(xs + t * C_);
    float a0 = 0.f, a1 = 0.f;
#pragma unroll
    for (int q = 0; q < C_ / 4; q += 2) {
      float4 v0 = xrow[q];
      float4 v1 = xrow[q + 1];
      a0 += wr[4 * q + 0] * v0.x + wr[4 * q + 1] * v0.y +
            wr[4 * q + 2] * v0.z + wr[4 * q + 3] * v0.w;
      a1 += wr[4 * q + 4] * v1.x + wr[4 * q + 5] * v1.y +
            wr[4 * q + 6] * v1.z + wr[4 * q + 7] * v1.w;
    }
    cur[((size_t)b * T_ + t0 + t) * H_ + tid] = a0 + a1 + bb;
  }
}

// ---------------------------------------------------------------------------
// K2: LIF scan per (b,h). Spikes stored as u8 (exact).
// ---------------------------------------------------------------------------
__global__ __launch_bounds__(64) void k_lif(const float* __restrict__ cur,
                                            unsigned char* __restrict__ spk) {
  const int b = blockIdx.x >> 2;
  const int h = ((blockIdx.x & 3) << 6) + threadIdx.x;
  const float* cp = cur + (size_t)b * T_ * H_ + h;
  unsigned char* sp = spk + (size_t)b * T_ * H_ + h;
  float mem = 0.f;
#pragma unroll 8
  for (int t = 0; t < T_; t++) {
    float c = cp[(size_t)t * H_];
    float reset = (mem > 1.0f) ? 1.0f : 0.0f;  // from previous mem
    mem = 0.9f * mem + c - reset;              // THR = 1
    sp[(size_t)t * H_] = (mem > 1.0f) ? (unsigned char)1 : (unsigned char)0;
  }
}

// ---------------------------------------------------------------------------
// K3: gx[m,g] = sum_k hcomb[m,k]*wih[g,k] + bih[g]   -> stored fp16
//     hcomb = [x (k<64) | spk (k>=64)], M=131072, K=320, N=768
// fp32 LDS-tiled GEMM: BM=128 BN=64 BK=32, 256 threads, 4x8 per-thread tile.
// ---------------------------------------------------------------------------
#define BM 128
#define BN 64
#define BK 32
__global__ __launch_bounds__(256) void k_gx(const float* __restrict__ x,
                                            const unsigned char* __restrict__ spk,
                                            const float* __restrict__ wih,
                                            const float* __restrict__ bih,
                                            _Float16* __restrict__ gx) {
  __shared__ float As[BK][BM];  // 16 KB
  __shared__ float Bs[BK][BN];  // 8 KB
  const int nb = blockIdx.x;
  const int mb = blockIdx.y;
  const int m0 = mb * BM, n0 = nb * BN;
  const int tid = threadIdx.x;
  const int tm = (tid & 31) * 4;
  const int tn = (tid >> 5) * 8;

  float acc[4][8] = {};

  for (int k0 = 0; k0 < 320; k0 += BK) {
    if (k0 < 64) {
#pragma unroll
      for (int i = 0; i < 4; i++) {
        int idx = tid + i * 256;
        int r = idx >> 3;
        int c4 = (idx & 7) * 4;
        float4 v = *(const float4*)(x + (size_t)(m0 + r) * C_ + k0 + c4);
        As[c4 + 0][r] = v.x; As[c4 + 1][r] = v.y;
        As[c4 + 2][r] = v.z; As[c4 + 3][r] = v.w;
      }
    } else {
#pragma unroll
      for (int i = 0; i < 4; i++) {
        int idx = tid + i * 256;
        int r = idx >> 3;
        int c4 = (idx & 7) * 4;
        uchar4 u = *(const uchar4*)(spk + (size_t)(m0 + r) * H_ + (k0 - 64) + c4);
        As[c4 + 0][r] = (float)u.x; As[c4 + 1][r] = (float)u.y;
        As[c4 + 2][r] = (float)u.z; As[c4 + 3][r] = (float)u.w;
      }
    }
#pragma unroll
    for (int i = 0; i < 2; i++) {
      int idx = tid + i * 256;
      int r = idx >> 3;
      int c4 = (idx & 7) * 4;
      float4 v = *(const float4*)(wih + (size_t)(n0 + r) * 320 + k0 + c4);
      Bs[c4 + 0][r] = v.x; Bs[c4 + 1][r] = v.y;
      Bs[c4 + 2][r] = v.z; Bs[c4 + 3][r] = v.w;
    }
    __syncthreads();
#pragma unroll
    for (int k = 0; k < BK; k++) {
      float a[4], bv[8];
      *(float4*)&a[0] = *(const float4*)&As[k][tm];
      *(float4*)&bv[0] = *(const float4*)&Bs[k][tn];
      *(float4*)&bv[4] = *(const float4*)&Bs[k][tn + 4];
#pragma unroll
      for (int i = 0; i < 4; i++)
#pragma unroll
        for (int jj = 0; jj < 8; jj++) acc[i][jj] += a[i] * bv[jj];
    }
    __syncthreads();
  }
#pragma unroll
  for (int i = 0; i < 4; i++) {
    size_t m = (size_t)(m0 + tm + i);
    h8 o;
#pragma unroll
    for (int jj = 0; jj < 8; jj++)
      o[jj] = (_Float16)(acc[i][jj] + bih[n0 + tn + jj]);
    *(h8*)(gx + m * G3_ + n0 + tn) = o;
  }
}

// ---------------------------------------------------------------------------
// K4: GRU scan via MFMA. One block per batch, 512 threads = 8 waves.
// gh[n] = sum_k whh[n,k]*h[k] done as mfma_f32_16x16x32_f16 with h replicated
// into all 16 A-rows (A-frag = wave-uniform-ish ds_read_b128 broadcast).
// Wave w owns N-cols [96w, 96w+96) = 6 tiles x full K (8 chunks of 32):
// 48 MFMA/step/wave, C accumulates in AGPRs (bhh folded into C init).
// B-frags = 192 regs/wave -> AGPR placement is FREE for MFMA (round-3
// lesson: v_dot2 can't read AGPRs, MFMA can — stop fighting the allocator).
// No cross-wave reduction (full K per wave). Gates on tid<256 (1 wave/SIMD).
// ---------------------------------------------------------------------------
__global__ __launch_bounds__(512, 2) void k_gru(const _Float16* __restrict__ gx,
                                                const float* __restrict__ whh,
                                                const float* __restrict__ bhh,
                                                const float* __restrict__ head_w,
                                                const float* __restrict__ head_b,
                                                float* __restrict__ out) {
  const int b = blockIdx.x;
  const int tid = threadIdx.x;
  const int lane = tid & 63;
  const int wave = tid >> 6;      // 0..7
  const int ln = lane & 15;       // n within tile
  const int qd = lane >> 4;       // 0..3 (k-quad)
  const int n0 = wave * 96;

  alignas(16) __shared__ _Float16 h16[H_];   // 512 B — fp16 h for A-frags
  __shared__ float gh[G3_];                  // 3 KB  — matvec result (+bhh)
  __shared__ _Float16 gxs16[G3_];            // 1.5 KB
  __shared__ float hbuf32[H_];               // 1 KB  — final h for head

  // --- B-fragments: whh[n0+i*16+ln][kc*32+qd*8 .. +8], fp32->fp16, once ---
  f16x8 wb[6][8];
#pragma unroll
  for (int i = 0; i < 6; i++) {
#pragma unroll
    for (int kc = 0; kc < 8; kc++) {
      const float4* p = (const float4*)(whh + (size_t)(n0 + i * 16 + ln) * H_ +
                                        kc * 32 + qd * 8);
      float4 lo = p[0], hi = p[1];
      f16x8 f;
      f[0] = (_Float16)lo.x; f[1] = (_Float16)lo.y;
      f[2] = (_Float16)lo.z; f[3] = (_Float16)lo.w;
      f[4] = (_Float16)hi.x; f[5] = (_Float16)hi.y;
      f[6] = (_Float16)hi.z; f[7] = (_Float16)hi.w;
      wb[i][kc] = f;
    }
  }
  // bias per owned n-column (folded into C init; all C rows identical)
  float bv[6];
#pragma unroll
  for (int i = 0; i < 6; i++) bv[i] = bhh[n0 + i * 16 + ln];

  if (tid < H_) h16[tid] = (_Float16)0.f;
  float hj = 0.f;  // per-thread h state (tid<256 only)
  __syncthreads();

  const _Float16* gxb = gx + (size_t)b * T_ * G3_;
  for (int t = 0; t < T_; t++) {
    // prefetch gx_t (2 fp16/thread for tid<384); vmcnt overlaps MFMA phase
    h2 gp;
    if (tid < 384) gp = ((const h2*)(gxb + (size_t)t * G3_))[tid];

    // --- MFMA phase: gh = whh·h + bhh ---
    f32x4 acc[6];
#pragma unroll
    for (int i = 0; i < 6; i++) acc[i] = (f32x4){bv[i], bv[i], bv[i], bv[i]};
#pragma unroll
    for (int kc = 0; kc < 8; kc++) {
      f16x8 a = *(const f16x8*)(h16 + kc * 32 + qd * 8);
#pragma unroll
      for (int i = 0; i < 6; i++)
        acc[i] = __builtin_amdgcn_mfma_f32_16x16x32_f16(a, wb[i][kc], acc[i], 0, 0, 0);
    }
    // readout: rows identical; quad-0 lanes write reg0 (row 0) per tile
    if (qd == 0) {
#pragma unroll
      for (int i = 0; i < 6; i++) gh[n0 + i * 16 + ln] = acc[i][0];
    }
    if (tid < 384) ((h2*)gxs16)[tid] = gp;
    __syncthreads();

    // --- gates phase (tid<256 = 1 wave per SIMD) ---
    if (tid < H_) {
      const int j = tid;
      float hr = gh[j], hz = gh[H_ + j], hn = gh[2 * H_ + j];
      float xr = (float)gxs16[j];
      float xz = (float)gxs16[H_ + j];
      float xn = (float)gxs16[2 * H_ + j];
      float r = 1.f / (1.f + __expf(-(xr + hr)));
      float z = 1.f / (1.f + __expf(-(xz + hz)));
      float pre = xn + r * hn;
      float e = __expf(2.f * pre);          // tanh(x) = 1 - 2/(e^{2x}+1)
      float n = 1.f - 2.f / (e + 1.f);
      hj = (1.f - z) * n + z * hj;
      h16[j] = (_Float16)hj;
    }
    __syncthreads();
  }

  if (tid < H_) hbuf32[tid] = hj;
  __syncthreads();

  // fused head
  if (tid < HOR_) {
    const float4* hw = (const float4*)(head_w + (size_t)tid * H_);
    const float4* hv4 = (const float4*)hbuf32;
    float acc = head_b[tid];
#pragma unroll
    for (int q = 0; q < H_ / 4; q++) {
      float4 w4 = hw[q];
      float4 v4 = hv4[q];
      acc += w4.x * v4.x + w4.y * v4.y + w4.z * v4.z + w4.w * v4.w;
    }
    out[(size_t)b * HOR_ + tid] = acc;
  }
}

// ---------------------------------------------------------------------------
extern "C" void kernel_launch(void* const* d_in, const int* in_sizes, int n_in,
                              void* d_out, int out_size, void* d_ws, size_t ws_size,
                              hipStream_t stream) {
  const float* x      = (const float*)d_in[0];
  const float* snn_w  = (const float*)d_in[1];
  const float* snn_b  = (const float*)d_in[2];
  const float* wih    = (const float*)d_in[3];
  const float* whh    = (const float*)d_in[4];
  const float* bih    = (const float*)d_in[5];
  const float* bhh    = (const float*)d_in[6];
  const float* head_w = (const float*)d_in[7];
  const float* head_b = (const float*)d_in[8];
  float* out = (float*)d_out;

  // ws layout (235 MB total, unchanged from round 2 — proven to fit):
  //   [0, 201326592)          gx fp16 [131072,768]
  //   [0, 134217728)          cur fp32 [131072,256] — alias, dead before k_gx
  //   [201326592, 234881024)  spk u8 [131072,256]
  char* ws = (char*)d_ws;
  _Float16* gx = (_Float16*)ws;
  float* cur = (float*)ws;
  unsigned char* spk = (unsigned char*)(ws + (size_t)201326592);

  k_cur<<<dim3(B_, T_ / K1_TT), 256, 0, stream>>>(x, snn_w, snn_b, cur);
  k_lif<<<dim3(256), 64, 0, stream>>>(cur, spk);
  k_gx<<<dim3(G3_ / BN, (B_ * T_) / BM), 256, 0, stream>>>(x, spk, wih, bih, gx);
  k_gru<<<dim3(B_), 512, 0, stream>>>(gx, whh, bhh, head_w, head_b, out);
}

// Round 5
// 3579.151 us; speedup vs baseline: 1.2806x; 1.2806x over previous
//
#include <hip/hip_runtime.h>
#include <cstdint>
#include <cstddef>

#define B_   64
#define T_   2048
#define C_   64
#define H_   256
#define G3_  768    // 3*H
#define HOR_ 96

typedef _Float16 h2 __attribute__((ext_vector_type(2)));
typedef _Float16 h8 __attribute__((ext_vector_type(8)));

// ---------------------------------------------------------------------------
// K1: cur[b,t,h] = sum_c x[b,t,c]*snn_w[h,c] + snn_b[h]     (fp32)
// ---------------------------------------------------------------------------
#define K1_TT 128
__global__ __launch_bounds__(256) void k_cur(const float* __restrict__ x,
                                             const float* __restrict__ w,
                                             const float* __restrict__ bias,
                                             float* __restrict__ cur) {
  __shared__ float xs[K1_TT * C_];  // 32 KB
  const int b = blockIdx.x;
  const int t0 = blockIdx.y * K1_TT;
  const int tid = threadIdx.x;

  const float4* xsrc = (const float4*)(x + ((size_t)b * T_ + t0) * C_);
  float4* xdst = (float4*)xs;
#pragma unroll
  for (int i = 0; i < (K1_TT * C_ / 4) / 256; i++)
    xdst[tid + i * 256] = xsrc[tid + i * 256];

  float wr[C_];
  const float4* wp = (const float4*)(w + (size_t)tid * C_);
#pragma unroll
  for (int q = 0; q < C_ / 4; q++) {
    float4 v = wp[q];
    wr[4 * q + 0] = v.x; wr[4 * q + 1] = v.y;
    wr[4 * q + 2] = v.z; wr[4 * q + 3] = v.w;
  }
  const float bb = bias[tid];
  __syncthreads();

  for (int t = 0; t < K1_TT; t++) {
    const float4* xrow = (const float4*)(xs + t * C_);
    float a0 = 0.f, a1 = 0.f;
#pragma unroll
    for (int q = 0; q < C_ / 4; q += 2) {
      float4 v0 = xrow[q];
      float4 v1 = xrow[q + 1];
      a0 += wr[4 * q + 0] * v0.x + wr[4 * q + 1] * v0.y +
            wr[4 * q + 2] * v0.z + wr[4 * q + 3] * v0.w;
      a1 += wr[4 * q + 4] * v1.x + wr[4 * q + 5] * v1.y +
            wr[4 * q + 6] * v1.z + wr[4 * q + 7] * v1.w;
    }
    cur[((size_t)b * T_ + t0 + t) * H_ + tid] = a0 + a1 + bb;
  }
}

// ---------------------------------------------------------------------------
// K2: LIF scan per (b,h). Spikes stored as u8 (exact).
// ---------------------------------------------------------------------------
__global__ __launch_bounds__(64) void k_lif(const float* __restrict__ cur,
                                            unsigned char* __restrict__ spk) {
  const int b = blockIdx.x >> 2;
  const int h = ((blockIdx.x & 3) << 6) + threadIdx.x;
  const float* cp = cur + (size_t)b * T_ * H_ + h;
  unsigned char* sp = spk + (size_t)b * T_ * H_ + h;
  float mem = 0.f;
#pragma unroll 8
  for (int t = 0; t < T_; t++) {
    float c = cp[(size_t)t * H_];
    float reset = (mem > 1.0f) ? 1.0f : 0.0f;  // from previous mem
    mem = 0.9f * mem + c - reset;              // THR = 1
    sp[(size_t)t * H_] = (mem > 1.0f) ? (unsigned char)1 : (unsigned char)0;
  }
}

// ---------------------------------------------------------------------------
// K3: gx[m,g] = sum_k hcomb[m,k]*wih[g,k] + bih[g]   -> stored fp16
//     hcomb = [x (k<64) | spk (k>=64)], M=131072, K=320, N=768
// fp32 LDS-tiled GEMM: BM=128 BN=64 BK=32, 256 threads, 4x8 per-thread tile.
// ---------------------------------------------------------------------------
#define BM 128
#define BN 64
#define BK 32
__global__ __launch_bounds__(256) void k_gx(const float* __restrict__ x,
                                            const unsigned char* __restrict__ spk,
                                            const float* __restrict__ wih,
                                            const float* __restrict__ bih,
                                            _Float16* __restrict__ gx) {
  __shared__ float As[BK][BM];  // 16 KB
  __shared__ float Bs[BK][BN];  // 8 KB
  const int nb = blockIdx.x;
  const int mb = blockIdx.y;
  const int m0 = mb * BM, n0 = nb * BN;
  const int tid = threadIdx.x;
  const int tm = (tid & 31) * 4;
  const int tn = (tid >> 5) * 8;

  float acc[4][8] = {};

  for (int k0 = 0; k0 < 320; k0 += BK) {
    if (k0 < 64) {
#pragma unroll
      for (int i = 0; i < 4; i++) {
        int idx = tid + i * 256;
        int r = idx >> 3;
        int c4 = (idx & 7) * 4;
        float4 v = *(const float4*)(x + (size_t)(m0 + r) * C_ + k0 + c4);
        As[c4 + 0][r] = v.x; As[c4 + 1][r] = v.y;
        As[c4 + 2][r] = v.z; As[c4 + 3][r] = v.w;
      }
    } else {
#pragma unroll
      for (int i = 0; i < 4; i++) {
        int idx = tid + i * 256;
        int r = idx >> 3;
        int c4 = (idx & 7) * 4;
        uchar4 u = *(const uchar4*)(spk + (size_t)(m0 + r) * H_ + (k0 - 64) + c4);
        As[c4 + 0][r] = (float)u.x; As[c4 + 1][r] = (float)u.y;
        As[c4 + 2][r] = (float)u.z; As[c4 + 3][r] = (float)u.w;
      }
    }
#pragma unroll
    for (int i = 0; i < 2; i++) {
      int idx = tid + i * 256;
      int r = idx >> 3;
      int c4 = (idx & 7) * 4;
      float4 v = *(const float4*)(wih + (size_t)(n0 + r) * 320 + k0 + c4);
      Bs[c4 + 0][r] = v.x; Bs[c4 + 1][r] = v.y;
      Bs[c4 + 2][r] = v.z; Bs[c4 + 3][r] = v.w;
    }
    __syncthreads();
#pragma unroll
    for (int k = 0; k < BK; k++) {
      float a[4], bv[8];
      *(float4*)&a[0] = *(const float4*)&As[k][tm];
      *(float4*)&bv[0] = *(const float4*)&Bs[k][tn];
      *(float4*)&bv[4] = *(const float4*)&Bs[k][tn + 4];
#pragma unroll
      for (int i = 0; i < 4; i++)
#pragma unroll
        for (int jj = 0; jj < 8; jj++) acc[i][jj] += a[i] * bv[jj];
    }
    __syncthreads();
  }
#pragma unroll
  for (int i = 0; i < 4; i++) {
    size_t m = (size_t)(m0 + tm + i);
    h8 o;
#pragma unroll
    for (int jj = 0; jj < 8; jj++)
      o[jj] = (_Float16)(acc[i][jj] + bih[n0 + tn + jj]);
    *(h8*)(gx + m * G3_ + n0 + tn) = o;
  }
}

// ---------------------------------------------------------------------------
// K4: GRU scan, fdot2 with lane-pair K-split. One block per batch, 512 thr.
// Lane l of wave w: j = 32w + (l>>1), kq = l&1 -> rows {j, j+256, j+512} x
// K-half [128*kq, +128) as 192 packed-h2 VGPRs. Pair-reduce via shfl_xor(1)
// (no LDS, no extra barrier); gates in-register (both lanes redundant);
// h fp16 double-buffered in LDS -> ONE barrier/step. gx_t prefetched t+1.
// sched_barrier(VALU|SALU|VMEM) every 4 h8-reads stops the compiler from
// hoisting all 16 LDS reads (round-3 lesson: hoist pushed peak regs > 256
// -> weights displaced to AGPRs -> accvgpr_read per fdot2 = 2x dot phase).
// ---------------------------------------------------------------------------
__global__ __launch_bounds__(512, 2) void k_gru(const _Float16* __restrict__ gx,
                                                const float* __restrict__ whh,
                                                const float* __restrict__ bhh,
                                                const float* __restrict__ head_w,
                                                const float* __restrict__ head_b,
                                                float* __restrict__ out) {
  const int b = blockIdx.x;
  const int tid = threadIdx.x;
  const int lane = tid & 63;
  const int wave = tid >> 6;          // 0..7
  const int j = wave * 32 + (lane >> 1);
  const int kq = lane & 1;
  const int k0 = kq * 128;

  alignas(16) __shared__ _Float16 h16[2][H_];  // 1 KB, double-buffered
  __shared__ float hbuf32[H_];                 // 1 KB — final h for head

  // weight slice -> packed half2 registers (192 VGPRs)
  h2 wr[64], wz[64], wn[64];
  {
    const float4* p0 = (const float4*)(whh + (size_t)j * H_ + k0);
    const float4* p1 = (const float4*)(whh + (size_t)(H_ + j) * H_ + k0);
    const float4* p2 = (const float4*)(whh + (size_t)(2 * H_ + j) * H_ + k0);
#pragma unroll
    for (int q = 0; q < 32; q++) {
      float4 a = p0[q];
      wr[2 * q].x = (_Float16)a.x; wr[2 * q].y = (_Float16)a.y;
      wr[2 * q + 1].x = (_Float16)a.z; wr[2 * q + 1].y = (_Float16)a.w;
      float4 c = p1[q];
      wz[2 * q].x = (_Float16)c.x; wz[2 * q].y = (_Float16)c.y;
      wz[2 * q + 1].x = (_Float16)c.z; wz[2 * q + 1].y = (_Float16)c.w;
      float4 d = p2[q];
      wn[2 * q].x = (_Float16)d.x; wn[2 * q].y = (_Float16)d.y;
      wn[2 * q + 1].x = (_Float16)d.z; wn[2 * q + 1].y = (_Float16)d.w;
    }
  }
  const float br_ = bhh[j], bz_ = bhh[H_ + j], bn_ = bhh[2 * H_ + j];

  if (tid < H_) { h16[0][tid] = (_Float16)0.f; }
  float hj = 0.f;  // h state for this lane's j (redundant across the pair)
  __syncthreads();

  const _Float16* gxb = gx + (size_t)b * T_ * G3_;
  // prefetch gx for t=0
  _Float16 pr = gxb[j], pz = gxb[H_ + j], pn = gxb[2 * H_ + j];

  int p = 0;
  for (int t = 0; t < T_; t++) {
    // consume this step's gx, then issue prefetch for t+1 (hidden under dots)
    float xr = (float)pr, xz = (float)pz, xn = (float)pn;
    {
      int tn_ = (t + 1 < T_) ? t + 1 : t;
      const _Float16* g = gxb + (size_t)tn_ * G3_;
      pr = g[j]; pz = g[H_ + j]; pn = g[2 * H_ + j];
    }

    // dot phase: 192 fdot2 over this lane's K-half
    const _Float16* hb = h16[p] + k0;
    float ar = 0.f, az = 0.f, an = 0.f;
#pragma unroll
    for (int g4 = 0; g4 < 4; g4++) {
#pragma unroll
      for (int kc = 0; kc < 4; kc++) {
        h8 hv = *(const h8*)(hb + (g4 * 4 + kc) * 8);
        const h2* hp = (const h2*)&hv;
#pragma unroll
        for (int i = 0; i < 4; i++) {
          int wi = (g4 * 4 + kc) * 4 + i;
          ar = __builtin_amdgcn_fdot2(wr[wi], hp[i], ar, false);
          az = __builtin_amdgcn_fdot2(wz[wi], hp[i], az, false);
          an = __builtin_amdgcn_fdot2(wn[wi], hp[i], an, false);
        }
      }
      // keep DS reads pinned to their group (allow VALU/SALU/VMEM to cross)
      __builtin_amdgcn_sched_barrier(2 | 4 | 16 | 32 | 64);
    }
    // pair reduction: lane kq=0 + kq=1 -> both lanes get full sums
    ar += __shfl_xor(ar, 1, 64);
    az += __shfl_xor(az, 1, 64);
    an += __shfl_xor(an, 1, 64);

    // gates (both lanes compute identically — no divergence, no LDS)
    float r = 1.f / (1.f + __expf(-(xr + ar + br_)));
    float z = 1.f / (1.f + __expf(-(xz + az + bz_)));
    float pre = xn + r * (an + bn_);
    float e = __expf(2.f * pre);          // tanh(x) = 1 - 2/(e^{2x}+1)
    float n = 1.f - 2.f / (e + 1.f);
    hj = (1.f - z) * n + z * hj;

    if (kq == 0) h16[p ^ 1][j] = (_Float16)hj;   // write next h buffer
    p ^= 1;
    __syncthreads();   // the ONLY barrier per step
  }

  if (kq == 0) hbuf32[j] = hj;
  __syncthreads();

  // fused head
  if (tid < HOR_) {
    const float4* hw = (const float4*)(head_w + (size_t)tid * H_);
    const float4* hv4 = (const float4*)hbuf32;
    float acc = head_b[tid];
#pragma unroll
    for (int q = 0; q < H_ / 4; q++) {
      float4 w4 = hw[q];
      float4 v4 = hv4[q];
      acc += w4.x * v4.x + w4.y * v4.y + w4.z * v4.z + w4.w * v4.w;
    }
    out[(size_t)b * HOR_ + tid] = acc;
  }
}

// ---------------------------------------------------------------------------
extern "C" void kernel_launch(void* const* d_in, const int* in_sizes, int n_in,
                              void* d_out, int out_size, void* d_ws, size_t ws_size,
                              hipStream_t stream) {
  const float* x      = (const float*)d_in[0];
  const float* snn_w  = (const float*)d_in[1];
  const float* snn_b  = (const float*)d_in[2];
  const float* wih    = (const float*)d_in[3];
  const float* whh    = (const float*)d_in[4];
  const float* bih    = (const float*)d_in[5];
  const float* bhh    = (const float*)d_in[6];
  const float* head_w = (const float*)d_in[7];
  const float* head_b = (const float*)d_in[8];
  float* out = (float*)d_out;

  // ws layout (235 MB total):
  //   [0, 201326592)          gx fp16 [131072,768]
  //   [0, 134217728)          cur fp32 [131072,256] — alias, dead before k_gx
  //   [201326592, 234881024)  spk u8 [131072,256]
  char* ws = (char*)d_ws;
  _Float16* gx = (_Float16*)ws;
  float* cur = (float*)ws;
  unsigned char* spk = (unsigned char*)(ws + (size_t)201326592);

  k_cur<<<dim3(B_, T_ / K1_TT), 256, 0, stream>>>(x, snn_w, snn_b, cur);
  k_lif<<<dim3(256), 64, 0, stream>>>(cur, spk);
  k_gx<<<dim3(G3_ / BN, (B_ * T_) / BM), 256, 0, stream>>>(x, spk, wih, bih, gx);
  k_gru<<<dim3(B_), 512, 0, stream>>>(gx, whh, bhh, head_w, head_b, out);
}